// Round 1
// 276.075 us; speedup vs baseline: 1.0476x; 1.0476x over previous
//
#include <hip/hip_runtime.h>
#include <stdint.h>

typedef float f32x4 __attribute__((ext_vector_type(4)));
typedef short s16x8 __attribute__((ext_vector_type(8)));
typedef unsigned short u16;
typedef unsigned short u16x4v __attribute__((ext_vector_type(4)));
typedef unsigned int u32x2 __attribute__((ext_vector_type(2)));

__device__ __forceinline__ u16 f2bf(float x) {
  union { float f; uint32_t u; } c; c.f = x;
  uint32_t u = c.u + 0x7fffu + ((c.u >> 16) & 1u);
  return (u16)(u >> 16);
}

// async global->LDS, 16B per lane. LDS dest = wave-uniform base + lane*16.
__device__ __forceinline__ void async16(void* lds, const void* g) {
  __builtin_amdgcn_global_load_lds(
      (const __attribute__((address_space(1))) uint32_t*)(uintptr_t)g,
      (__attribute__((address_space(3))) uint32_t*)(uintptr_t)lds,
      16, 0, 0);
}

// pack two f32 into one dword of 2 bf16 (round-half-up): lo=f0, hi=f1
__device__ __forceinline__ uint32_t pack_bf2(float f0, float f1) {
  uint32_t u0 = __builtin_bit_cast(uint32_t, f0) + 0x8000u;
  uint32_t u1 = __builtin_bit_cast(uint32_t, f1) + 0x8000u;
  return __builtin_amdgcn_perm(u1, u0, 0x07060302u);
}

#define CSCALE 0.18033688011112042f  /* 1/sqrt(64) * log2(e) */

// ---------------- fp32 -> bf16 cast (x) ----------------
__global__ __launch_bounds__(256) void cvt_bf16_kernel(
    const float* __restrict__ in, u16* __restrict__ out) {
  size_t i = ((size_t)blockIdx.x * 256 + threadIdx.x) * 4;
  f32x4 v = *(const f32x4*)(in + i);
  u16x4v o;
#pragma unroll
  for (int j = 0; j < 4; ++j) o[j] = f2bf(v[j]);
  *(u16x4v*)(out + i) = o;
}

// ------------- transpose + cast: in[R][C] f32 -> out[C][R] bf16 -------------
__global__ __launch_bounds__(256) void transpose_cvt(
    const float* __restrict__ in, u16* __restrict__ out, int R, int C) {
  __shared__ float t[32][33];
  int tx = threadIdx.x & 31, ty = threadIdx.x >> 5;
  int r0 = blockIdx.y * 32, c0 = blockIdx.x * 32;
#pragma unroll
  for (int i = 0; i < 4; ++i)
    t[ty + i * 8][tx] = in[(size_t)(r0 + ty + i * 8) * C + c0 + tx];
  __syncthreads();
#pragma unroll
  for (int i = 0; i < 4; ++i)
    out[(size_t)(c0 + ty + i * 8) * R + r0 + tx] = f2bf(t[tx][ty + i * 8]);
}

// ---------------- 256x128x(K=1024) bf16 MFMA GEMM, B^T input ----------------
// Pipelined rewrite (T2+T3/T4+T5 stack):
//   - tile 256(M) x 128(N), BK=64, 512 threads = 8 waves as 4Mx2N,
//     wave tile 64x64 (acc 4x4 f32x4).
//   - LDS triple-buffered: stage tile t+2 while computing tile t. Per tile:
//     6 global_load_lds x16B per thread (A: 4 calls, B: 2 calls).
//   - counted vmcnt: at tile end wait vmcnt(6) -> tile t+1's 6 calls retired
//     (oldest), tile t+2's 6 stay in flight. Never drains to 0 in steady
//     state. ONE raw s_barrier per BK=64 tile (32 MFMA/wave per barrier).
//   - LDS XOR swizzle, both-sides-or-neither: LDS slot s of row r holds
//     global 16B chunk s^(r&7) (applied on the per-lane GLOBAL source addr,
//     LDS dest stays linear per async16's constraint); reads apply the same
//     involution -> ds_read_b128 frag reads are 2-way max (free).
//   - s_setprio(1) around each 16-MFMA cluster.
//   - bijective XCD swizzle on flattened block id (nwg % 8 == 0).
// MODE 0: epilogue scatters qkv -> q[bh][n][d] (pre-scaled by CSCALE),
//         k[bh][n][d], v^T[bh][d][n] (bf16)
// MODE 1: epilogue writes fp32 out[row][col] + bias
template <int MODE>
__global__ __launch_bounds__(512, 2) void gemm_bt(
    const u16* __restrict__ A, const u16* __restrict__ Bt,
    const float* __restrict__ bias,
    u16* __restrict__ qd, u16* __restrict__ kd, u16* __restrict__ vtd,
    float* __restrict__ outd) {
  __shared__ u16 lA[3][256 * 64];  // 96 KB: [buf][row 0..255][64 bf16, swz]
  __shared__ u16 lB[3][128 * 64];  // 48 KB
  const int tid = threadIdx.x;   // 0..511
  const int lane = tid & 63;
  const int quad = lane >> 4;
  const int l15 = lane & 15;
  const int wv = tid >> 6;       // 0..7
  const int wm = wv >> 1;        // 0..3 -> 64-row slice
  const int wn = wv & 1;         // 0..1 -> 64-col slice

  constexpr int GX = (MODE == 0) ? 24 : 8;   // N / 128
  constexpr int CPX = (GX * 32) / 8;         // blocks per XCD
  int bid = blockIdx.y * GX + blockIdx.x;
  bid = (bid & 7) * CPX + (bid >> 3);        // XCD-contiguous remap
  const int m0 = (bid / GX) * 256;
  const int n0 = (bid % GX) * 128;

  // ---- staging descriptors: chunk c = call*512 + tid; row=c>>3, slot=c&7;
  //      slot holds global chunk slot^(row&7). K-slice t -> +t*128 bytes.
  const char* aSrc[4];
  int aOff[4];
#pragma unroll
  for (int c2 = 0; c2 < 4; ++c2) {
    int c = c2 * 512 + tid, r = c >> 3, s = c & 7, g = s ^ (r & 7);
    aSrc[c2] = (const char*)A + (size_t)(m0 + r) * 2048 + g * 16;
    aOff[c2] = c * 16;
  }
  const char* bSrc[2];
  int bOff[2];
#pragma unroll
  for (int c2 = 0; c2 < 2; ++c2) {
    int c = c2 * 512 + tid, r = c >> 3, s = c & 7, g = s ^ (r & 7);
    bSrc[c2] = (const char*)Bt + (size_t)(n0 + r) * 2048 + g * 16;
    bOff[c2] = c * 16;
  }

  f32x4 acc[4][4] = {};
  const int swA = l15 & 7;            // read-side XOR (row&7 == l15&7)
  const int arow = wm * 64 + l15;     // + i*16
  const int brow = wn * 64 + l15;     // + j*16

  // one phase = half a K-tile (kh = k 0..31 / 32..63): 8 ds_read_b128,
  // 3 stage calls for tile t+2, 16 MFMA under setprio.
  auto phase = [&](const u16* bA, const u16* bB, int kh, int nb, int ko,
                   bool stg, int sel) {
    s16x8 af[4], bq[4];
#pragma unroll
    for (int i = 0; i < 4; ++i)
      af[i] = *(const s16x8*)((const char*)bA + (arow + i * 16) * 128 +
                              (((kh << 2) | quad) ^ swA) * 16);
#pragma unroll
    for (int j = 0; j < 4; ++j)
      bq[j] = *(const s16x8*)((const char*)bB + (brow + j * 16) * 128 +
                              (((kh << 2) | quad) ^ swA) * 16);
    if (stg) {
      if (sel == 0) {
        async16((char*)lA[nb] + aOff[0], aSrc[0] + ko);
        async16((char*)lA[nb] + aOff[1], aSrc[1] + ko);
        async16((char*)lB[nb] + bOff[0], bSrc[0] + ko);
      } else {
        async16((char*)lA[nb] + aOff[2], aSrc[2] + ko);
        async16((char*)lA[nb] + aOff[3], aSrc[3] + ko);
        async16((char*)lB[nb] + bOff[1], bSrc[1] + ko);
      }
    }
    __builtin_amdgcn_s_setprio(1);
#pragma unroll
    for (int i = 0; i < 4; ++i)
#pragma unroll
      for (int j = 0; j < 4; ++j)
        acc[i][j] =
            __builtin_amdgcn_mfma_f32_16x16x32_bf16(af[i], bq[j], acc[i][j], 0, 0, 0);
    __builtin_amdgcn_s_setprio(0);
  };

  // ---- prologue: stage tiles 0 and 1; wait tile 0 (vmcnt leaves tile 1's 6)
#pragma unroll
  for (int c2 = 0; c2 < 4; ++c2) async16((char*)lA[0] + aOff[c2], aSrc[c2]);
#pragma unroll
  for (int c2 = 0; c2 < 2; ++c2) async16((char*)lB[0] + bOff[c2], bSrc[c2]);
#pragma unroll
  for (int c2 = 0; c2 < 4; ++c2) async16((char*)lA[1] + aOff[c2], aSrc[c2] + 128);
#pragma unroll
  for (int c2 = 0; c2 < 2; ++c2) async16((char*)lB[1] + bOff[c2], bSrc[c2] + 128);
  asm volatile("s_waitcnt vmcnt(6)" ::: "memory");
  __builtin_amdgcn_s_barrier();

  // ---- main loop: 16 K-tiles. t<14 stage tile t+2; steady-state vmcnt(6).
  int bufc = 0;
#pragma unroll 1
  for (int t = 0; t < 14; ++t) {
    const int nb = bufc >= 1 ? bufc - 1 : 2;  // (bufc+2)%3
    const int ko = (t + 2) * 128;
    phase(lA[bufc], lB[bufc], 0, nb, ko, true, 0);
    phase(lA[bufc], lB[bufc], 1, nb, ko, true, 1);
    asm volatile("s_waitcnt vmcnt(6)" ::: "memory");  // tile t+1 resident
    __builtin_amdgcn_s_barrier();
    bufc = bufc < 2 ? bufc + 1 : 0;
  }
  // t = 14: nothing left to stage; drain tile 15's loads.
  phase(lA[bufc], lB[bufc], 0, 0, 0, false, 0);
  phase(lA[bufc], lB[bufc], 1, 0, 0, false, 1);
  asm volatile("s_waitcnt vmcnt(0)" ::: "memory");
  __builtin_amdgcn_s_barrier();
  bufc = bufc < 2 ? bufc + 1 : 0;
  // t = 15
  phase(lA[bufc], lB[bufc], 0, 0, 0, false, 0);
  phase(lA[bufc], lB[bufc], 1, 0, 0, false, 1);

  // ---- epilogue (unchanged math; wave geometry 4Mx2N) ----
  float bj[4];
#pragma unroll
  for (int j = 0; j < 4; ++j) bj[j] = bias[n0 + wn * 64 + j * 16 + l15];

  if (MODE == 0) {
#pragma unroll
    for (int j = 0; j < 4; ++j) {
      int col = n0 + wn * 64 + j * 16 + l15;
      int which = col >> 10;         // 0=q 1=k 2=v (uniform per j)
      int rem = col & 1023;
      int h = rem >> 6, d = rem & 63;
#pragma unroll
      for (int i = 0; i < 4; ++i) {
#pragma unroll
        for (int r = 0; r < 4; ++r) {
          int row = m0 + wm * 64 + i * 16 + quad * 4 + r;  // C/D: row=(lane>>4)*4+reg
          int b = row >> 11, s = row & 2047;
          float t = acc[i][j][r] + bj[j];
          if (which == 0) t *= CSCALE;  // pre-scale Q for softmax-in-exp2 domain
          u16 v = f2bf(t);
          size_t bh = (size_t)(b * 16 + h);
          if (which == 0)      qd[(bh * 2048 + s) * 64 + d] = v;
          else if (which == 1) kd[(bh * 2048 + s) * 64 + d] = v;
          else                 vtd[(bh * 64 + d) * 2048 + s] = v;  // transposed
        }
      }
    }
  } else {
#pragma unroll
    for (int i = 0; i < 4; ++i)
#pragma unroll
      for (int r = 0; r < 4; ++r) {
        int row = m0 + wm * 64 + i * 16 + quad * 4 + r;
#pragma unroll
        for (int j = 0; j < 4; ++j) {
          int col = n0 + wn * 64 + j * 16 + l15;
          outd[(size_t)row * 1024 + col] = acc[i][j][r] + bj[j];
        }
      }
  }
}

// ---------------- fused flash attention v3: shared LDS K/V tiles ------------
// Block = 4 waves x 64q = 256 q-rows, iterating ALL 2048 keys together.
// K (8KB) + V^T (8KB) per 64-key tile staged via global_load_lds (width 16),
// double-buffered (32KB), ONE barrier per tile: stage(t+1) issues first,
// compute(t) hides the latency, the barrier's vmcnt drain lands after.
// XOR swizzle (chunk ^= row&7) on the STAGING SOURCE address keeps the LDS
// dest lane-contiguous (async16 constraint) and makes ds_read_b128 A-frag
// reads conflict-free. Per-wave VMEM drops from 16 loads/tile (R2..R6,
// ~5000cyc latency wall) to 4 async16/tile shared by the block.
// S^T = K*Q^T; P^T C-layout -> PV B-operand via permlane quad swaps.
// No key-split => no combine; epilogue stores directly.
// Q pre-scaled by CSCALE; denominator l = P*1 via ones-MFMA.
// grid 512 = 2 blocks/CU; ~230 unified regs -> 2 waves/SIMD (reg-bound, ok).
__global__ __launch_bounds__(256, 2) void attn_fused(
    const u16* __restrict__ Q, const u16* __restrict__ Kd,
    const u16* __restrict__ Vt, u16* __restrict__ Od) {
  __shared__ u16 lK[2][4096];  // [buf][key 0..63][8 chunks of 16B, swizzled]
  __shared__ u16 lV[2][4096];  // [buf][d 0..63][8 chunks of 16B, swizzled]
  const int tid = threadIdx.x;
  const int lane = tid & 63;
  const int wv = tid >> 6;
  const int quad = lane >> 4;
  const int l15 = lane & 15;
  const int bh = blockIdx.x & 63;   // bh-minor: XCD affinity (8 bh/XCD)
  const int qt = blockIdx.x >> 6;   // 0..7
  const int q0 = qt * 256 + wv * 64;

  const u16* qb = Q + ((size_t)bh * 2048 + q0) * 64;
  const char* kbB = (const char*)(Kd + (size_t)bh * 2048 * 64);  // row 128B
  const char* vbB = (const char*)(Vt + (size_t)bh * 64 * 2048);  // row 4096B

  // staging maps: chunk c (0..511) -> row c>>3, slot c&7 holds src chunk
  // (c&7)^(row&7). Thread handles c0=tid, c1=tid+256 for both K and V.
  const int r0 = tid >> 3, s0 = tid & 7;
  const int r1 = r0 + 32;
  const int kOff0 = r0 * 128 + ((s0 ^ (r0 & 7)) * 16);
  const int kOff1 = r1 * 128 + ((s0 ^ (r1 & 7)) * 16);
  const int vOff0 = r0 * 4096 + ((s0 ^ (r0 & 7)) * 16);
  const int vOff1 = r1 * 4096 + ((s0 ^ (r1 & 7)) * 16);

  auto stage = [&](int kbase, int buf) {
    const char* ks = kbB + (size_t)kbase * 128;
    const char* vs = vbB + (size_t)kbase * 2;
    async16((char*)lK[buf] + tid * 16, ks + kOff0);
    async16((char*)lK[buf] + 4096 + tid * 16, ks + kOff1);
    async16((char*)lV[buf] + tid * 16, vs + vOff0);
    async16((char*)lV[buf] + 4096 + tid * 16, vs + vOff1);
  };

  // Q B-frags: B[k=d][n=q], lane: n=l15, k=quad*8+j  -> 16B contiguous
  s16x8 qfr[4][2];
#pragma unroll
  for (int qf = 0; qf < 4; ++qf)
#pragma unroll
    for (int kd2 = 0; kd2 < 2; ++kd2)
      qfr[qf][kd2] = *(const s16x8*)(qb + (qf * 16 + l15) * 64 + kd2 * 32 + quad * 8);

  s16x8 ones;
#pragma unroll
  for (int j = 0; j < 8; ++j) ones[j] = (short)0x3F80;  // bf16 1.0

  f32x4 oacc[4][4] = {};  // [df][qf]  out^T: d=df*16+quad*4+r, q=qf*16+l15
  f32x4 lacc[4] = {};     // [qf] denominator (all regs equal)

  const int sw = (l15 & 7);  // read-side XOR

  auto compute = [&](int buf) {
    const char* bK = (const char*)lK[buf];
    const char* bV = (const char*)lV[buf];

    // S^T = K * Q^T, per-mf to keep st transient; exp+pack immediately
    uint32_t pd[4][4][2];
#pragma unroll
    for (int mf = 0; mf < 4; ++mf) {
      const char* kr = bK + (mf * 16 + l15) * 128;
      s16x8 kf0 = *(const s16x8*)(kr + ((quad ^ sw) * 16));
      s16x8 kf1 = *(const s16x8*)(kr + (((4 + quad) ^ sw) * 16));
      f32x4 st[4];
#pragma unroll
      for (int qf = 0; qf < 4; ++qf) {
        f32x4 a = {};
        a = __builtin_amdgcn_mfma_f32_16x16x32_bf16(kf0, qfr[qf][0], a, 0, 0, 0);
        a = __builtin_amdgcn_mfma_f32_16x16x32_bf16(kf1, qfr[qf][1], a, 0, 0, 0);
        st[qf] = a;
      }
#pragma unroll
      for (int qf = 0; qf < 4; ++qf) {
        float p0 = __builtin_amdgcn_exp2f(st[qf][0]);
        float p1 = __builtin_amdgcn_exp2f(st[qf][1]);
        float p2 = __builtin_amdgcn_exp2f(st[qf][2]);
        float p3 = __builtin_amdgcn_exp2f(st[qf][3]);
        pd[mf][qf][0] = pack_bf2(p0, p1);
        pd[mf][qf][1] = pack_bf2(p2, p3);
      }
    }

    // V^T A-frags from LDS: A[m=d][k=key]
    s16x8 vf[4][2];
#pragma unroll
    for (int df = 0; df < 4; ++df) {
      const char* vr = bV + (df * 16 + l15) * 128;
#pragma unroll
      for (int kh = 0; kh < 2; ++kh)
        vf[df][kh] = *(const s16x8*)(vr + (((kh * 4 + quad) ^ sw) * 16));
    }

    // C-layout -> B-operand layout via gfx950 permlane swaps
#pragma unroll
    for (int kh = 0; kh < 2; ++kh)
#pragma unroll
      for (int qf = 0; qf < 4; ++qf)
#pragma unroll
        for (int pi = 0; pi < 2; ++pi) {
          uint32_t x = pd[2 * kh][qf][pi];
          uint32_t y = pd[2 * kh + 1][qf][pi];
          asm("s_nop 1\n\t"
              "v_permlane32_swap_b32 %0, %1\n\t"
              "s_nop 0\n\t"
              "v_permlane16_swap_b32 %0, %1"
              : "+v"(x), "+v"(y));
          pd[2 * kh][qf][pi] = x;
          pd[2 * kh + 1][qf][pi] = y;
        }

    // PV: out^T += V^T * P^T ; l += 1 * P^T
#pragma unroll
    for (int kh = 0; kh < 2; ++kh)
#pragma unroll
      for (int qf = 0; qf < 4; ++qf) {
        union { s16x8 h; uint32_t u[4]; } bfr;
        bfr.u[0] = pd[2 * kh][qf][0];
        bfr.u[1] = pd[2 * kh][qf][1];
        bfr.u[2] = pd[2 * kh + 1][qf][0];
        bfr.u[3] = pd[2 * kh + 1][qf][1];
#pragma unroll
        for (int df = 0; df < 4; ++df)
          oacc[df][qf] = __builtin_amdgcn_mfma_f32_16x16x32_bf16(vf[df][kh], bfr.h, oacc[df][qf], 0, 0, 0);
        lacc[qf] = __builtin_amdgcn_mfma_f32_16x16x32_bf16(ones, bfr.h, lacc[qf], 0, 0, 0);
      }
  };

  stage(0, 0);
  __syncthreads();
#pragma unroll 1
  for (int t = 0; t < 32; t += 2) {
    if (t + 1 < 32) stage((t + 1) * 64, 1);
    compute(0);
    __syncthreads();
    if (t + 2 < 32) stage((t + 2) * 64, 0);
    compute(1);
    __syncthreads();
  }

  // epilogue: normalize and store bf16 out^T -> attO[b][s][h*64+d]
  const int b = bh >> 4, h = bh & 15;
  float inv[4];
#pragma unroll
  for (int qf = 0; qf < 4; ++qf) inv[qf] = 1.0f / lacc[qf][0];
#pragma unroll
  for (int qf = 0; qf < 4; ++qf) {
    u16* rowp = Od + ((size_t)b * 2048 + q0 + qf * 16 + l15) * 1024 + h * 64;
#pragma unroll
    for (int df = 0; df < 4; ++df) {
      u32x2 w;
      w.x = pack_bf2(oacc[df][qf][0] * inv[qf], oacc[df][qf][1] * inv[qf]);
      w.y = pack_bf2(oacc[df][qf][2] * inv[qf], oacc[df][qf][3] * inv[qf]);
      *(u32x2*)(rowp + df * 16 + quad * 4) = w;
    }
  }
}

extern "C" void kernel_launch(void* const* d_in, const int* in_sizes, int n_in,
                              void* d_out, int out_size, void* d_ws, size_t ws_size,
                              hipStream_t stream) {
  const float* x = (const float*)d_in[0];
  const float* w_qkv = (const float*)d_in[1];
  const float* b_qkv = (const float*)d_in[2];
  const float* w_out = (const float*)d_in[3];
  const float* b_out = (const float*)d_in[4];
  float* out = (float*)d_out;
  char* ws = (char*)d_ws;

  // workspace layout (bytes)
  u16* xb    = (u16*)(ws + 0);         // 16,777,216  x as bf16 [8192][1024]
  u16* wqkvT = (u16*)(ws + 16777216);  //  6,291,456  [3072][1024]
  u16* woutT = (u16*)(ws + 23068672);  //  2,097,152  [1024][1024]
  u16* qw    = (u16*)(ws + 25165824);  // 16,777,216  [64][2048][64] (pre-scaled)
  u16* kw    = (u16*)(ws + 41943040);  // 16,777,216  [64][2048][64]
  u16* vtw   = (u16*)(ws + 58720256);  // 16,777,216  [64][64][2048]
  u16* attO  = (u16*)(ws + 75497472);  // 16,777,216  [8192][1024]
  // total 92,274,688 bytes

  cvt_bf16_kernel<<<8192, 256, 0, stream>>>(x, xb);
  transpose_cvt<<<dim3(96, 32), 256, 0, stream>>>(w_qkv, wqkvT, 1024, 3072);
  transpose_cvt<<<dim3(32, 32), 256, 0, stream>>>(w_out, woutT, 1024, 1024);
  gemm_bt<0><<<dim3(24, 32), 512, 0, stream>>>(xb, wqkvT, b_qkv, qw, kw, vtw, nullptr);
  attn_fused<<<512, 256, 0, stream>>>(qw, kw, vtw, attO);
  gemm_bt<1><<<dim3(8, 32), 512, 0, stream>>>(attO, woutT, b_out, nullptr, nullptr, nullptr, out);
}

// Round 2
// 272.880 us; speedup vs baseline: 1.0599x; 1.0117x over previous
//
#include <hip/hip_runtime.h>
#include <stdint.h>

typedef float f32x4 __attribute__((ext_vector_type(4)));
typedef short s16x8 __attribute__((ext_vector_type(8)));
typedef unsigned short u16;
typedef unsigned short u16x4v __attribute__((ext_vector_type(4)));
typedef unsigned int u32x2 __attribute__((ext_vector_type(2)));

__device__ __forceinline__ u16 f2bf(float x) {
  union { float f; uint32_t u; } c; c.f = x;
  uint32_t u = c.u + 0x7fffu + ((c.u >> 16) & 1u);
  return (u16)(u >> 16);
}

// async global->LDS, 16B per lane. LDS dest = wave-uniform base + lane*16.
__device__ __forceinline__ void async16(void* lds, const void* g) {
  __builtin_amdgcn_global_load_lds(
      (const __attribute__((address_space(1))) uint32_t*)(uintptr_t)g,
      (__attribute__((address_space(3))) uint32_t*)(uintptr_t)lds,
      16, 0, 0);
}

// pack two f32 into one dword of 2 bf16 (round-half-up): lo=f0, hi=f1
__device__ __forceinline__ uint32_t pack_bf2(float f0, float f1) {
  uint32_t u0 = __builtin_bit_cast(uint32_t, f0) + 0x8000u;
  uint32_t u1 = __builtin_bit_cast(uint32_t, f1) + 0x8000u;
  return __builtin_amdgcn_perm(u1, u0, 0x07060302u);
}

#define CSCALE 0.18033688011112042f  /* 1/sqrt(64) * log2(e) */

// ---------------- fp32 -> bf16 cast (x) ----------------
__global__ __launch_bounds__(256) void cvt_bf16_kernel(
    const float* __restrict__ in, u16* __restrict__ out) {
  size_t i = ((size_t)blockIdx.x * 256 + threadIdx.x) * 4;
  f32x4 v = *(const f32x4*)(in + i);
  u16x4v o;
#pragma unroll
  for (int j = 0; j < 4; ++j) o[j] = f2bf(v[j]);
  *(u16x4v*)(out + i) = o;
}

// ------------- transpose + cast: in[R][C] f32 -> out[C][R] bf16 -------------
__global__ __launch_bounds__(256) void transpose_cvt(
    const float* __restrict__ in, u16* __restrict__ out, int R, int C) {
  __shared__ float t[32][33];
  int tx = threadIdx.x & 31, ty = threadIdx.x >> 5;
  int r0 = blockIdx.y * 32, c0 = blockIdx.x * 32;
#pragma unroll
  for (int i = 0; i < 4; ++i)
    t[ty + i * 8][tx] = in[(size_t)(r0 + ty + i * 8) * C + c0 + tx];
  __syncthreads();
#pragma unroll
  for (int i = 0; i < 4; ++i)
    out[(size_t)(c0 + ty + i * 8) * R + r0 + tx] = f2bf(t[tx][ty + i * 8]);
}

// ---------------- 256x128x(K=1024) bf16 MFMA GEMM, B^T input ----------------
// R2: m201-style phase schedule, fully unrolled K-loop.
//   - 16 K-tiles (BK=64) FULLY UNROLLED with compile-time buffer indices:
//     alias analysis can prove ds_read(buf a) does not alias in-flight
//     global_load_lds writes(buf b) -> no spurious compiler vmcnt(0) drains;
//     all LDS/global offsets fold to immediates.
//   - per half-tile phase: {8 ds_read_b128 + 3 async16 for tile t+2}
//     -> s_barrier -> lgkmcnt(0) -> setprio(1) -> 16 MFMA -> setprio(0)
//     -> s_barrier.  ONE counted s_waitcnt vmcnt(6) per tile (tile t+1
//     resident, tile t+2's 6 loads stay in flight); drains only at t=14/15.
//   - triple-buffered LDS (144 KB), 8 waves 4Mx2N, XOR-swizzled (unchanged
//     layout from R1 -> bit-identical numerics).
template <int MODE>
__global__ __launch_bounds__(512, 2) void gemm_bt(
    const u16* __restrict__ A, const u16* __restrict__ Bt,
    const float* __restrict__ bias,
    u16* __restrict__ qd, u16* __restrict__ kd, u16* __restrict__ vtd,
    float* __restrict__ outd) {
  __shared__ u16 lA[3][256 * 64];  // 96 KB: [buf][row 0..255][64 bf16, swz]
  __shared__ u16 lB[3][128 * 64];  // 48 KB
  const int tid = threadIdx.x;   // 0..511
  const int lane = tid & 63;
  const int quad = lane >> 4;
  const int l15 = lane & 15;
  const int wv = tid >> 6;       // 0..7
  const int wm = wv >> 1;        // 0..3 -> 64-row slice
  const int wn = wv & 1;         // 0..1 -> 64-col slice

  constexpr int GX = (MODE == 0) ? 24 : 8;   // N / 128
  constexpr int CPX = (GX * 32) / 8;         // blocks per XCD
  int bid = blockIdx.y * GX + blockIdx.x;
  bid = (bid & 7) * CPX + (bid >> 3);        // XCD-contiguous remap
  const int m0 = (bid / GX) * 256;
  const int n0 = (bid % GX) * 128;

  // ---- staging descriptors: chunk c = call*512 + tid; row=c>>3, slot=c&7;
  //      slot holds global chunk slot^(row&7). K-slice t -> +t*128 bytes.
  const char* aSrc0; const char* aSrc1; const char* aSrc2; const char* aSrc3;
  const char* bSrc0; const char* bSrc1;
  int aOff0, aOff1, aOff2, aOff3, bOff0, bOff1;
  {
    int c, r, s, g;
    c = 0 * 512 + tid; r = c >> 3; s = c & 7; g = s ^ (r & 7);
    aSrc0 = (const char*)A + (size_t)(m0 + r) * 2048 + g * 16; aOff0 = c * 16;
    c = 1 * 512 + tid; r = c >> 3; s = c & 7; g = s ^ (r & 7);
    aSrc1 = (const char*)A + (size_t)(m0 + r) * 2048 + g * 16; aOff1 = c * 16;
    c = 2 * 512 + tid; r = c >> 3; s = c & 7; g = s ^ (r & 7);
    aSrc2 = (const char*)A + (size_t)(m0 + r) * 2048 + g * 16; aOff2 = c * 16;
    c = 3 * 512 + tid; r = c >> 3; s = c & 7; g = s ^ (r & 7);
    aSrc3 = (const char*)A + (size_t)(m0 + r) * 2048 + g * 16; aOff3 = c * 16;
    c = 0 * 512 + tid; r = c >> 3; s = c & 7; g = s ^ (r & 7);
    bSrc0 = (const char*)Bt + (size_t)(n0 + r) * 2048 + g * 16; bOff0 = c * 16;
    c = 1 * 512 + tid; r = c >> 3; s = c & 7; g = s ^ (r & 7);
    bSrc1 = (const char*)Bt + (size_t)(n0 + r) * 2048 + g * 16; bOff1 = c * 16;
  }

  f32x4 acc[4][4] = {};
  const int swA = l15 & 7;                    // read-side XOR (row&7 == l15&7)
  const int aBase = (wm * 64 + l15) * 128;    // + i*2048 + swz
  const int bBase = (wn * 64 + l15) * 128;    // + j*2048 + swz
  const int swz0 = (quad ^ swA) * 16;         // kh=0 chunk
  const int swz1 = ((4 | quad) ^ swA) * 16;   // kh=1 chunk
  const char* lAc = (const char*)lA;
  const char* lBc = (const char*)lB;
  char* lAw = (char*)lA;
  char* lBw = (char*)lB;

  // one phase = half a K-tile. CB/NB/KH/KO are compile-time constants.
#define GPH(CB, NB, KH, KO, STG)                                              \
  {                                                                           \
    s16x8 af[4], bq[4];                                                       \
    const int so = (KH) ? swz1 : swz0;                                        \
    _Pragma("unroll") for (int i = 0; i < 4; ++i)                             \
      af[i] = *(const s16x8*)(lAc + (CB) * 32768 + aBase + i * 2048 + so);    \
    _Pragma("unroll") for (int j = 0; j < 4; ++j)                             \
      bq[j] = *(const s16x8*)(lBc + (CB) * 16384 + bBase + j * 2048 + so);    \
    if (STG) {                                                                \
      if ((KH) == 0) {                                                        \
        async16(lAw + (NB) * 32768 + aOff0, aSrc0 + (KO));                    \
        async16(lAw + (NB) * 32768 + aOff1, aSrc1 + (KO));                    \
        async16(lBw + (NB) * 16384 + bOff0, bSrc0 + (KO));                    \
      } else {                                                                \
        async16(lAw + (NB) * 32768 + aOff2, aSrc2 + (KO));                    \
        async16(lAw + (NB) * 32768 + aOff3, aSrc3 + (KO));                    \
        async16(lBw + (NB) * 16384 + bOff1, bSrc1 + (KO));                    \
      }                                                                       \
    }                                                                         \
    __builtin_amdgcn_sched_barrier(0);                                        \
    __builtin_amdgcn_s_barrier();                                             \
    asm volatile("s_waitcnt lgkmcnt(0)" ::: "memory");                        \
    __builtin_amdgcn_sched_barrier(0);                                        \
    __builtin_amdgcn_s_setprio(1);                                            \
    _Pragma("unroll") for (int i = 0; i < 4; ++i)                             \
      _Pragma("unroll") for (int j = 0; j < 4; ++j)                           \
        acc[i][j] = __builtin_amdgcn_mfma_f32_16x16x32_bf16(af[i], bq[j],     \
                                                            acc[i][j], 0, 0, 0); \
    __builtin_amdgcn_s_setprio(0);                                            \
    __builtin_amdgcn_sched_barrier(0);                                        \
  }

  // ---- prologue: stage tiles 0 (buf0) and 1 (buf1); wait tile 0 only.
  async16(lAw + aOff0, aSrc0);
  async16(lAw + aOff1, aSrc1);
  async16(lAw + aOff2, aSrc2);
  async16(lAw + aOff3, aSrc3);
  async16(lBw + bOff0, bSrc0);
  async16(lBw + bOff1, bSrc1);
  async16(lAw + 32768 + aOff0, aSrc0 + 128);
  async16(lAw + 32768 + aOff1, aSrc1 + 128);
  async16(lAw + 32768 + aOff2, aSrc2 + 128);
  async16(lAw + 32768 + aOff3, aSrc3 + 128);
  async16(lBw + 16384 + bOff0, bSrc0 + 128);
  async16(lBw + 16384 + bOff1, bSrc1 + 128);
  asm volatile("s_waitcnt vmcnt(6)" ::: "memory");
  __builtin_amdgcn_s_barrier();

  // ---- main loop, fully unrolled: tiles 0..13 stage tile t+2.
#define GTILE(T)                                                              \
  GPH((T) % 3, ((T) + 2) % 3, 0, ((T) + 2) * 128, 1);                         \
  GPH((T) % 3, ((T) + 2) % 3, 1, ((T) + 2) * 128, 1);                         \
  asm volatile("s_waitcnt vmcnt(6)" ::: "memory");                            \
  __builtin_amdgcn_s_barrier();

  GTILE(0) GTILE(1) GTILE(2) GTILE(3) GTILE(4) GTILE(5) GTILE(6)
  GTILE(7) GTILE(8) GTILE(9) GTILE(10) GTILE(11) GTILE(12) GTILE(13)
#undef GTILE

  // t = 14 (buf 2): nothing to stage; drain tile 15's 6 loads at the end.
  GPH(2, 0, 0, 0, 0);
  GPH(2, 0, 1, 0, 0);
  asm volatile("s_waitcnt vmcnt(0)" ::: "memory");
  __builtin_amdgcn_s_barrier();
  // t = 15 (buf 0): last tile, no trailing barrier needed.
  GPH(0, 0, 0, 0, 0);
  GPH(0, 0, 1, 0, 0);
#undef GPH

  // ---- epilogue (unchanged math; wave geometry 4Mx2N) ----
  float bj[4];
#pragma unroll
  for (int j = 0; j < 4; ++j) bj[j] = bias[n0 + wn * 64 + j * 16 + l15];

  if (MODE == 0) {
#pragma unroll
    for (int j = 0; j < 4; ++j) {
      int col = n0 + wn * 64 + j * 16 + l15;
      int which = col >> 10;         // 0=q 1=k 2=v (uniform per j)
      int rem = col & 1023;
      int h = rem >> 6, d = rem & 63;
#pragma unroll
      for (int i = 0; i < 4; ++i) {
#pragma unroll
        for (int r = 0; r < 4; ++r) {
          int row = m0 + wm * 64 + i * 16 + quad * 4 + r;  // C/D: row=(lane>>4)*4+reg
          int b = row >> 11, s = row & 2047;
          float t = acc[i][j][r] + bj[j];
          if (which == 0) t *= CSCALE;  // pre-scale Q for softmax-in-exp2 domain
          u16 v = f2bf(t);
          size_t bh = (size_t)(b * 16 + h);
          if (which == 0)      qd[(bh * 2048 + s) * 64 + d] = v;
          else if (which == 1) kd[(bh * 2048 + s) * 64 + d] = v;
          else                 vtd[(bh * 64 + d) * 2048 + s] = v;  // transposed
        }
      }
    }
  } else {
#pragma unroll
    for (int i = 0; i < 4; ++i)
#pragma unroll
      for (int r = 0; r < 4; ++r) {
        int row = m0 + wm * 64 + i * 16 + quad * 4 + r;
#pragma unroll
        for (int j = 0; j < 4; ++j) {
          int col = n0 + wn * 64 + j * 16 + l15;
          outd[(size_t)row * 1024 + col] = acc[i][j][r] + bj[j];
        }
      }
  }
}

// ---------------- fused flash attention v3: shared LDS K/V tiles ------------
// Block = 4 waves x 64q = 256 q-rows, iterating ALL 2048 keys together.
// K (8KB) + V^T (8KB) per 64-key tile staged via global_load_lds (width 16),
// double-buffered (32KB), ONE barrier per tile: stage(t+1) issues first,
// compute(t) hides the latency, the barrier's vmcnt drain lands after.
// XOR swizzle (chunk ^= row&7) on the STAGING SOURCE address keeps the LDS
// dest lane-contiguous (async16 constraint) and makes ds_read_b128 A-frag
// reads conflict-free. S^T = K*Q^T; P^T C-layout -> PV B-operand via
// permlane quad swaps. Q pre-scaled by CSCALE; denominator via ones-MFMA.
__global__ __launch_bounds__(256, 2) void attn_fused(
    const u16* __restrict__ Q, const u16* __restrict__ Kd,
    const u16* __restrict__ Vt, u16* __restrict__ Od) {
  __shared__ u16 lK[2][4096];  // [buf][key 0..63][8 chunks of 16B, swizzled]
  __shared__ u16 lV[2][4096];  // [buf][d 0..63][8 chunks of 16B, swizzled]
  const int tid = threadIdx.x;
  const int lane = tid & 63;
  const int wv = tid >> 6;
  const int quad = lane >> 4;
  const int l15 = lane & 15;
  const int bh = blockIdx.x & 63;   // bh-minor: XCD affinity (8 bh/XCD)
  const int qt = blockIdx.x >> 6;   // 0..7
  const int q0 = qt * 256 + wv * 64;

  const u16* qb = Q + ((size_t)bh * 2048 + q0) * 64;
  const char* kbB = (const char*)(Kd + (size_t)bh * 2048 * 64);  // row 128B
  const char* vbB = (const char*)(Vt + (size_t)bh * 64 * 2048);  // row 4096B

  // staging maps: chunk c (0..511) -> row c>>3, slot c&7 holds src chunk
  // (c&7)^(row&7). Thread handles c0=tid, c1=tid+256 for both K and V.
  const int r0 = tid >> 3, s0 = tid & 7;
  const int r1 = r0 + 32;
  const int kOff0 = r0 * 128 + ((s0 ^ (r0 & 7)) * 16);
  const int kOff1 = r1 * 128 + ((s0 ^ (r1 & 7)) * 16);
  const int vOff0 = r0 * 4096 + ((s0 ^ (r0 & 7)) * 16);
  const int vOff1 = r1 * 4096 + ((s0 ^ (r1 & 7)) * 16);

  auto stage = [&](int kbase, int buf) {
    const char* ks = kbB + (size_t)kbase * 128;
    const char* vs = vbB + (size_t)kbase * 2;
    async16((char*)lK[buf] + tid * 16, ks + kOff0);
    async16((char*)lK[buf] + 4096 + tid * 16, ks + kOff1);
    async16((char*)lV[buf] + tid * 16, vs + vOff0);
    async16((char*)lV[buf] + 4096 + tid * 16, vs + vOff1);
  };

  // Q B-frags: B[k=d][n=q], lane: n=l15, k=quad*8+j  -> 16B contiguous
  s16x8 qfr[4][2];
#pragma unroll
  for (int qf = 0; qf < 4; ++qf)
#pragma unroll
    for (int kd2 = 0; kd2 < 2; ++kd2)
      qfr[qf][kd2] = *(const s16x8*)(qb + (qf * 16 + l15) * 64 + kd2 * 32 + quad * 8);

  s16x8 ones;
#pragma unroll
  for (int j = 0; j < 8; ++j) ones[j] = (short)0x3F80;  // bf16 1.0

  f32x4 oacc[4][4] = {};  // [df][qf]  out^T: d=df*16+quad*4+r, q=qf*16+l15
  f32x4 lacc[4] = {};     // [qf] denominator (all regs equal)

  const int sw = (l15 & 7);  // read-side XOR

  auto compute = [&](int buf) {
    const char* bK = (const char*)lK[buf];
    const char* bV = (const char*)lV[buf];

    // S^T = K * Q^T, per-mf to keep st transient; exp+pack immediately
    uint32_t pd[4][4][2];
#pragma unroll
    for (int mf = 0; mf < 4; ++mf) {
      const char* kr = bK + (mf * 16 + l15) * 128;
      s16x8 kf0 = *(const s16x8*)(kr + ((quad ^ sw) * 16));
      s16x8 kf1 = *(const s16x8*)(kr + (((4 + quad) ^ sw) * 16));
      f32x4 st[4];
#pragma unroll
      for (int qf = 0; qf < 4; ++qf) {
        f32x4 a = {};
        a = __builtin_amdgcn_mfma_f32_16x16x32_bf16(kf0, qfr[qf][0], a, 0, 0, 0);
        a = __builtin_amdgcn_mfma_f32_16x16x32_bf16(kf1, qfr[qf][1], a, 0, 0, 0);
        st[qf] = a;
      }
#pragma unroll
      for (int qf = 0; qf < 4; ++qf) {
        float p0 = __builtin_amdgcn_exp2f(st[qf][0]);
        float p1 = __builtin_amdgcn_exp2f(st[qf][1]);
        float p2 = __builtin_amdgcn_exp2f(st[qf][2]);
        float p3 = __builtin_amdgcn_exp2f(st[qf][3]);
        pd[mf][qf][0] = pack_bf2(p0, p1);
        pd[mf][qf][1] = pack_bf2(p2, p3);
      }
    }

    // V^T A-frags from LDS: A[m=d][k=key]
    s16x8 vf[4][2];
#pragma unroll
    for (int df = 0; df < 4; ++df) {
      const char* vr = bV + (df * 16 + l15) * 128;
#pragma unroll
      for (int kh = 0; kh < 2; ++kh)
        vf[df][kh] = *(const s16x8*)(vr + (((kh * 4 + quad) ^ sw) * 16));
    }

    // C-layout -> B-operand layout via gfx950 permlane swaps
#pragma unroll
    for (int kh = 0; kh < 2; ++kh)
#pragma unroll
      for (int qf = 0; qf < 4; ++qf)
#pragma unroll
        for (int pi = 0; pi < 2; ++pi) {
          uint32_t x = pd[2 * kh][qf][pi];
          uint32_t y = pd[2 * kh + 1][qf][pi];
          asm("s_nop 1\n\t"
              "v_permlane32_swap_b32 %0, %1\n\t"
              "s_nop 0\n\t"
              "v_permlane16_swap_b32 %0, %1"
              : "+v"(x), "+v"(y));
          pd[2 * kh][qf][pi] = x;
          pd[2 * kh + 1][qf][pi] = y;
        }

    // PV: out^T += V^T * P^T ; l += 1 * P^T
#pragma unroll
    for (int kh = 0; kh < 2; ++kh)
#pragma unroll
      for (int qf = 0; qf < 4; ++qf) {
        union { s16x8 h; uint32_t u[4]; } bfr;
        bfr.u[0] = pd[2 * kh][qf][0];
        bfr.u[1] = pd[2 * kh][qf][1];
        bfr.u[2] = pd[2 * kh + 1][qf][0];
        bfr.u[3] = pd[2 * kh + 1][qf][1];
#pragma unroll
        for (int df = 0; df < 4; ++df)
          oacc[df][qf] = __builtin_amdgcn_mfma_f32_16x16x32_bf16(vf[df][kh], bfr.h, oacc[df][qf], 0, 0, 0);
        lacc[qf] = __builtin_amdgcn_mfma_f32_16x16x32_bf16(ones, bfr.h, lacc[qf], 0, 0, 0);
      }
  };

  stage(0, 0);
  __syncthreads();
#pragma unroll 1
  for (int t = 0; t < 32; t += 2) {
    if (t + 1 < 32) stage((t + 1) * 64, 1);
    compute(0);
    __syncthreads();
    if (t + 2 < 32) stage((t + 2) * 64, 0);
    compute(1);
    __syncthreads();
  }

  // epilogue: normalize and store bf16 out^T -> attO[b][s][h*64+d]
  const int b = bh >> 4, h = bh & 15;
  float inv[4];
#pragma unroll
  for (int qf = 0; qf < 4; ++qf) inv[qf] = 1.0f / lacc[qf][0];
#pragma unroll
  for (int qf = 0; qf < 4; ++qf) {
    u16* rowp = Od + ((size_t)b * 2048 + q0 + qf * 16 + l15) * 1024 + h * 64;
#pragma unroll
    for (int df = 0; df < 4; ++df) {
      u32x2 w;
      w.x = pack_bf2(oacc[df][qf][0] * inv[qf], oacc[df][qf][1] * inv[qf]);
      w.y = pack_bf2(oacc[df][qf][2] * inv[qf], oacc[df][qf][3] * inv[qf]);
      *(u32x2*)(rowp + df * 16 + quad * 4) = w;
    }
  }
}

extern "C" void kernel_launch(void* const* d_in, const int* in_sizes, int n_in,
                              void* d_out, int out_size, void* d_ws, size_t ws_size,
                              hipStream_t stream) {
  const float* x = (const float*)d_in[0];
  const float* w_qkv = (const float*)d_in[1];
  const float* b_qkv = (const float*)d_in[2];
  const float* w_out = (const float*)d_in[3];
  const float* b_out = (const float*)d_in[4];
  float* out = (float*)d_out;
  char* ws = (char*)d_ws;

  // workspace layout (bytes)
  u16* xb    = (u16*)(ws + 0);         // 16,777,216  x as bf16 [8192][1024]
  u16* wqkvT = (u16*)(ws + 16777216);  //  6,291,456  [3072][1024]
  u16* woutT = (u16*)(ws + 23068672);  //  2,097,152  [1024][1024]
  u16* qw    = (u16*)(ws + 25165824);  // 16,777,216  [64][2048][64] (pre-scaled)
  u16* kw    = (u16*)(ws + 41943040);  // 16,777,216  [64][2048][64]
  u16* vtw   = (u16*)(ws + 58720256);  // 16,777,216  [64][64][2048]
  u16* attO  = (u16*)(ws + 75497472);  // 16,777,216  [8192][1024]
  // total 92,274,688 bytes

  cvt_bf16_kernel<<<8192, 256, 0, stream>>>(x, xb);
  transpose_cvt<<<dim3(96, 32), 256, 0, stream>>>(w_qkv, wqkvT, 1024, 3072);
  transpose_cvt<<<dim3(32, 32), 256, 0, stream>>>(w_out, woutT, 1024, 1024);
  gemm_bt<0><<<dim3(24, 32), 512, 0, stream>>>(xb, wqkvT, b_qkv, qw, kw, vtw, nullptr);
  attn_fused<<<512, 256, 0, stream>>>(qw, kw, vtw, attO);
  gemm_bt<1><<<dim3(8, 32), 512, 0, stream>>>(attO, woutT, b_out, nullptr, nullptr, nullptr, out);
}

// Round 4
// 252.837 us; speedup vs baseline: 1.1439x; 1.0793x over previous
//
#include <hip/hip_runtime.h>
#include <stdint.h>

typedef float f32x4 __attribute__((ext_vector_type(4)));
typedef short s16x8 __attribute__((ext_vector_type(8)));
typedef unsigned short u16;
typedef unsigned short u16x4v __attribute__((ext_vector_type(4)));
typedef unsigned int u32x2 __attribute__((ext_vector_type(2)));

__device__ __forceinline__ u16 f2bf(float x) {
  union { float f; uint32_t u; } c; c.f = x;
  uint32_t u = c.u + 0x7fffu + ((c.u >> 16) & 1u);
  return (u16)(u >> 16);
}

// async global->LDS, 16B per lane. LDS dest = wave-uniform base + lane*16.
__device__ __forceinline__ void async16(void* lds, const void* g) {
  __builtin_amdgcn_global_load_lds(
      (const __attribute__((address_space(1))) uint32_t*)(uintptr_t)g,
      (__attribute__((address_space(3))) uint32_t*)(uintptr_t)lds,
      16, 0, 0);
}

// pack two f32 into one dword of 2 bf16 (round-half-up): lo=f0, hi=f1
__device__ __forceinline__ uint32_t pack_bf2(float f0, float f1) {
  uint32_t u0 = __builtin_bit_cast(uint32_t, f0) + 0x8000u;
  uint32_t u1 = __builtin_bit_cast(uint32_t, f1) + 0x8000u;
  return __builtin_amdgcn_perm(u1, u0, 0x07060302u);
}

#define CSCALE 0.18033688011112042f  /* 1/sqrt(64) * log2(e) */

// ---------------- fp32 -> bf16 cast (x) ----------------
__global__ __launch_bounds__(256) void cvt_bf16_kernel(
    const float* __restrict__ in, u16* __restrict__ out) {
  size_t i = ((size_t)blockIdx.x * 256 + threadIdx.x) * 4;
  f32x4 v = *(const f32x4*)(in + i);
  u16x4v o;
#pragma unroll
  for (int j = 0; j < 4; ++j) o[j] = f2bf(v[j]);
  *(u16x4v*)(out + i) = o;
}

// ------------- transpose + cast: in[R][C] f32 -> out[C][R] bf16 -------------
__global__ __launch_bounds__(256) void transpose_cvt(
    const float* __restrict__ in, u16* __restrict__ out, int R, int C) {
  __shared__ float t[32][33];
  int tx = threadIdx.x & 31, ty = threadIdx.x >> 5;
  int r0 = blockIdx.y * 32, c0 = blockIdx.x * 32;
#pragma unroll
  for (int i = 0; i < 4; ++i)
    t[ty + i * 8][tx] = in[(size_t)(r0 + ty + i * 8) * C + c0 + tx];
  __syncthreads();
#pragma unroll
  for (int i = 0; i < 4; ++i)
    out[(size_t)(c0 + ty + i * 8) * R + r0 + tx] = f2bf(t[tx][ty + i * 8]);
}

// ---------------- 256x128x(K=1024) bf16 MFMA GEMM, B^T input ----------------
// R4: L2-resident XCD band mapping (sole surviving R3 change; cvt_pk revert).
//   HW dispatch round-robins consecutive blockIdx across the 8 XCDs, so
//   xcd = bid & 7. R2's swizzle gave each XCD n%8==x -> ~6.2 MB resident vs
//   4 MB L2 -> thrash, supply-bound phases (~2050 cyc vs 512 cyc MFMA).
//   New mapping: XCD x owns m-band {4x + (jj&3)}, n = jj>>2 (jj = bid>>3;
//   bijective: bid = (4n + (m&3))*8 + (m>>2)). A working set pinned at
//   2 MB/XCD (A fetched ONCE chip-wide: bands disjoint), B window ~2 MB.
//   Phase schedule unchanged from R2 (full unroll, counted vmcnt(6),
//   barrier-pair, setprio, XOR-swizzled LDS).
template <int MODE>
__global__ __launch_bounds__(512, 2) void gemm_bt(
    const u16* __restrict__ A, const u16* __restrict__ Bt,
    const float* __restrict__ bias,
    u16* __restrict__ qd, u16* __restrict__ kd, u16* __restrict__ vtd,
    float* __restrict__ outd) {
  __shared__ u16 lA[3][256 * 64];  // 96 KB: [buf][row 0..255][64 bf16, swz]
  __shared__ u16 lB[3][128 * 64];  // 48 KB
  const int tid = threadIdx.x;   // 0..511
  const int lane = tid & 63;
  const int quad = lane >> 4;
  const int l15 = lane & 15;
  const int wv = tid >> 6;       // 0..7
  const int wm = wv >> 1;        // 0..3 -> 64-row slice
  const int wn = wv & 1;         // 0..1 -> 64-col slice

  constexpr int GX = (MODE == 0) ? 24 : 8;   // N / 128
  const int bid = blockIdx.y * GX + blockIdx.x;
  const int xcd = bid & 7;                   // HW XCD of this block
  const int jj = bid >> 3;                   // sequence within XCD
  const int m0 = (xcd * 4 + (jj & 3)) * 256; // m-band pinned to XCD
  const int n0 = (jj >> 2) * 128;            // n streams within XCD

  // ---- staging descriptors: chunk c = call*512 + tid; row=c>>3, slot=c&7;
  //      slot holds global chunk slot^(row&7). K-slice t -> +t*128 bytes.
  const char* aSrc0; const char* aSrc1; const char* aSrc2; const char* aSrc3;
  const char* bSrc0; const char* bSrc1;
  int aOff0, aOff1, aOff2, aOff3, bOff0, bOff1;
  {
    int c, r, s, g;
    c = 0 * 512 + tid; r = c >> 3; s = c & 7; g = s ^ (r & 7);
    aSrc0 = (const char*)A + (size_t)(m0 + r) * 2048 + g * 16; aOff0 = c * 16;
    c = 1 * 512 + tid; r = c >> 3; s = c & 7; g = s ^ (r & 7);
    aSrc1 = (const char*)A + (size_t)(m0 + r) * 2048 + g * 16; aOff1 = c * 16;
    c = 2 * 512 + tid; r = c >> 3; s = c & 7; g = s ^ (r & 7);
    aSrc2 = (const char*)A + (size_t)(m0 + r) * 2048 + g * 16; aOff2 = c * 16;
    c = 3 * 512 + tid; r = c >> 3; s = c & 7; g = s ^ (r & 7);
    aSrc3 = (const char*)A + (size_t)(m0 + r) * 2048 + g * 16; aOff3 = c * 16;
    c = 0 * 512 + tid; r = c >> 3; s = c & 7; g = s ^ (r & 7);
    bSrc0 = (const char*)Bt + (size_t)(n0 + r) * 2048 + g * 16; bOff0 = c * 16;
    c = 1 * 512 + tid; r = c >> 3; s = c & 7; g = s ^ (r & 7);
    bSrc1 = (const char*)Bt + (size_t)(n0 + r) * 2048 + g * 16; bOff1 = c * 16;
  }

  f32x4 acc[4][4] = {};
  const int swA = l15 & 7;                    // read-side XOR (row&7 == l15&7)
  const int aBase = (wm * 64 + l15) * 128;    // + i*2048 + swz
  const int bBase = (wn * 64 + l15) * 128;    // + j*2048 + swz
  const int swz0 = (quad ^ swA) * 16;         // kh=0 chunk
  const int swz1 = ((4 | quad) ^ swA) * 16;   // kh=1 chunk
  const char* lAc = (const char*)lA;
  const char* lBc = (const char*)lB;
  char* lAw = (char*)lA;
  char* lBw = (char*)lB;

  // one phase = half a K-tile. CB/NB/KH/KO are compile-time constants.
#define GPH(CB, NB, KH, KO, STG)                                              \
  {                                                                           \
    s16x8 af[4], bq[4];                                                       \
    const int so = (KH) ? swz1 : swz0;                                        \
    _Pragma("unroll") for (int i = 0; i < 4; ++i)                             \
      af[i] = *(const s16x8*)(lAc + (CB) * 32768 + aBase + i * 2048 + so);    \
    _Pragma("unroll") for (int j = 0; j < 4; ++j)                             \
      bq[j] = *(const s16x8*)(lBc + (CB) * 16384 + bBase + j * 2048 + so);    \
    if (STG) {                                                                \
      if ((KH) == 0) {                                                        \
        async16(lAw + (NB) * 32768 + aOff0, aSrc0 + (KO));                    \
        async16(lAw + (NB) * 32768 + aOff1, aSrc1 + (KO));                    \
        async16(lBw + (NB) * 16384 + bOff0, bSrc0 + (KO));                    \
      } else {                                                                \
        async16(lAw + (NB) * 32768 + aOff2, aSrc2 + (KO));                    \
        async16(lAw + (NB) * 32768 + aOff3, aSrc3 + (KO));                    \
        async16(lBw + (NB) * 16384 + bOff1, bSrc1 + (KO));                    \
      }                                                                       \
    }                                                                         \
    __builtin_amdgcn_sched_barrier(0);                                        \
    __builtin_amdgcn_s_barrier();                                             \
    asm volatile("s_waitcnt lgkmcnt(0)" ::: "memory");                        \
    __builtin_amdgcn_sched_barrier(0);                                        \
    __builtin_amdgcn_s_setprio(1);                                            \
    _Pragma("unroll") for (int i = 0; i < 4; ++i)                             \
      _Pragma("unroll") for (int j = 0; j < 4; ++j)                           \
        acc[i][j] = __builtin_amdgcn_mfma_f32_16x16x32_bf16(af[i], bq[j],     \
                                                            acc[i][j], 0, 0, 0); \
    __builtin_amdgcn_s_setprio(0);                                            \
    __builtin_amdgcn_sched_barrier(0);                                        \
  }

  // ---- prologue: stage tiles 0 (buf0) and 1 (buf1); wait tile 0 only.
  async16(lAw + aOff0, aSrc0);
  async16(lAw + aOff1, aSrc1);
  async16(lAw + aOff2, aSrc2);
  async16(lAw + aOff3, aSrc3);
  async16(lBw + bOff0, bSrc0);
  async16(lBw + bOff1, bSrc1);
  async16(lAw + 32768 + aOff0, aSrc0 + 128);
  async16(lAw + 32768 + aOff1, aSrc1 + 128);
  async16(lAw + 32768 + aOff2, aSrc2 + 128);
  async16(lAw + 32768 + aOff3, aSrc3 + 128);
  async16(lBw + 16384 + bOff0, bSrc0 + 128);
  async16(lBw + 16384 + bOff1, bSrc1 + 128);
  asm volatile("s_waitcnt vmcnt(6)" ::: "memory");
  __builtin_amdgcn_s_barrier();

  // ---- main loop, fully unrolled: tiles 0..13 stage tile t+2.
#define GTILE(T)                                                              \
  GPH((T) % 3, ((T) + 2) % 3, 0, ((T) + 2) * 128, 1);                         \
  GPH((T) % 3, ((T) + 2) % 3, 1, ((T) + 2) * 128, 1);                         \
  asm volatile("s_waitcnt vmcnt(6)" ::: "memory");                            \
  __builtin_amdgcn_s_barrier();

  GTILE(0) GTILE(1) GTILE(2) GTILE(3) GTILE(4) GTILE(5) GTILE(6)
  GTILE(7) GTILE(8) GTILE(9) GTILE(10) GTILE(11) GTILE(12) GTILE(13)
#undef GTILE

  // t = 14 (buf 2): nothing to stage; drain tile 15's 6 loads at the end.
  GPH(2, 0, 0, 0, 0);
  GPH(2, 0, 1, 0, 0);
  asm volatile("s_waitcnt vmcnt(0)" ::: "memory");
  __builtin_amdgcn_s_barrier();
  // t = 15 (buf 0): last tile, no trailing barrier needed.
  GPH(0, 0, 0, 0, 0);
  GPH(0, 0, 1, 0, 0);
#undef GPH

  // ---- epilogue (unchanged math; wave geometry 4Mx2N) ----
  float bj[4];
#pragma unroll
  for (int j = 0; j < 4; ++j) bj[j] = bias[n0 + wn * 64 + j * 16 + l15];

  if (MODE == 0) {
#pragma unroll
    for (int j = 0; j < 4; ++j) {
      int col = n0 + wn * 64 + j * 16 + l15;
      int which = col >> 10;         // 0=q 1=k 2=v (uniform per j)
      int rem = col & 1023;
      int h = rem >> 6, d = rem & 63;
#pragma unroll
      for (int i = 0; i < 4; ++i) {
#pragma unroll
        for (int r = 0; r < 4; ++r) {
          int row = m0 + wm * 64 + i * 16 + quad * 4 + r;  // C/D: row=(lane>>4)*4+reg
          int b = row >> 11, s = row & 2047;
          float t = acc[i][j][r] + bj[j];
          if (which == 0) t *= CSCALE;  // pre-scale Q for softmax-in-exp2 domain
          u16 v = f2bf(t);
          size_t bh = (size_t)(b * 16 + h);
          if (which == 0)      qd[(bh * 2048 + s) * 64 + d] = v;
          else if (which == 1) kd[(bh * 2048 + s) * 64 + d] = v;
          else                 vtd[(bh * 64 + d) * 2048 + s] = v;  // transposed
        }
      }
    }
  } else {
#pragma unroll
    for (int i = 0; i < 4; ++i)
#pragma unroll
      for (int r = 0; r < 4; ++r) {
        int row = m0 + wm * 64 + i * 16 + quad * 4 + r;
#pragma unroll
        for (int j = 0; j < 4; ++j) {
          int col = n0 + wn * 64 + j * 16 + l15;
          outd[(size_t)row * 1024 + col] = acc[i][j][r] + bj[j];
        }
      }
  }
}

// ---------------- fused flash attention v3: shared LDS K/V tiles ------------
// Block = 4 waves x 64q = 256 q-rows, iterating ALL 2048 keys together.
// K (8KB) + V^T (8KB) per 64-key tile staged via global_load_lds (width 16),
// double-buffered (32KB), ONE barrier per tile: stage(t+1) issues first,
// compute(t) hides the latency, the barrier's vmcnt drain lands after.
// XOR swizzle (chunk ^= row&7) on the STAGING SOURCE address keeps the LDS
// dest lane-contiguous (async16 constraint) and makes ds_read_b128 A-frag
// reads conflict-free. S^T = K*Q^T; P^T C-layout -> PV B-operand via
// permlane quad swaps. Q pre-scaled by CSCALE; denominator via ones-MFMA.
// R4: P-packing reverted to pack_bf2 (R3's v_cvt_pk_bf16_f32 asm broke
// numerics; m240 also rates hand-written cvt_pk a perf loss).
__global__ __launch_bounds__(256, 2) void attn_fused(
    const u16* __restrict__ Q, const u16* __restrict__ Kd,
    const u16* __restrict__ Vt, u16* __restrict__ Od) {
  __shared__ u16 lK[2][4096];  // [buf][key 0..63][8 chunks of 16B, swizzled]
  __shared__ u16 lV[2][4096];  // [buf][d 0..63][8 chunks of 16B, swizzled]
  const int tid = threadIdx.x;
  const int lane = tid & 63;
  const int wv = tid >> 6;
  const int quad = lane >> 4;
  const int l15 = lane & 15;
  const int bh = blockIdx.x & 63;   // bh-minor: XCD affinity (8 bh/XCD)
  const int qt = blockIdx.x >> 6;   // 0..7
  const int q0 = qt * 256 + wv * 64;

  const u16* qb = Q + ((size_t)bh * 2048 + q0) * 64;
  const char* kbB = (const char*)(Kd + (size_t)bh * 2048 * 64);  // row 128B
  const char* vbB = (const char*)(Vt + (size_t)bh * 64 * 2048);  // row 4096B

  // staging maps: chunk c (0..511) -> row c>>3, slot c&7 holds src chunk
  // (c&7)^(row&7). Thread handles c0=tid, c1=tid+256 for both K and V.
  const int r0 = tid >> 3, s0 = tid & 7;
  const int r1 = r0 + 32;
  const int kOff0 = r0 * 128 + ((s0 ^ (r0 & 7)) * 16);
  const int kOff1 = r1 * 128 + ((s0 ^ (r1 & 7)) * 16);
  const int vOff0 = r0 * 4096 + ((s0 ^ (r0 & 7)) * 16);
  const int vOff1 = r1 * 4096 + ((s0 ^ (r1 & 7)) * 16);

  auto stage = [&](int kbase, int buf) {
    const char* ks = kbB + (size_t)kbase * 128;
    const char* vs = vbB + (size_t)kbase * 2;
    async16((char*)lK[buf] + tid * 16, ks + kOff0);
    async16((char*)lK[buf] + 4096 + tid * 16, ks + kOff1);
    async16((char*)lV[buf] + tid * 16, vs + vOff0);
    async16((char*)lV[buf] + 4096 + tid * 16, vs + vOff1);
  };

  // Q B-frags: B[k=d][n=q], lane: n=l15, k=quad*8+j  -> 16B contiguous
  s16x8 qfr[4][2];
#pragma unroll
  for (int qf = 0; qf < 4; ++qf)
#pragma unroll
    for (int kd2 = 0; kd2 < 2; ++kd2)
      qfr[qf][kd2] = *(const s16x8*)(qb + (qf * 16 + l15) * 64 + kd2 * 32 + quad * 8);

  s16x8 ones;
#pragma unroll
  for (int j = 0; j < 8; ++j) ones[j] = (short)0x3F80;  // bf16 1.0

  f32x4 oacc[4][4] = {};  // [df][qf]  out^T: d=df*16+quad*4+r, q=qf*16+l15
  f32x4 lacc[4] = {};     // [qf] denominator (all regs equal)

  const int sw = (l15 & 7);  // read-side XOR

  auto compute = [&](int buf) {
    const char* bK = (const char*)lK[buf];
    const char* bV = (const char*)lV[buf];

    // S^T = K * Q^T, per-mf to keep st transient; exp+pack immediately
    uint32_t pd[4][4][2];
#pragma unroll
    for (int mf = 0; mf < 4; ++mf) {
      const char* kr = bK + (mf * 16 + l15) * 128;
      s16x8 kf0 = *(const s16x8*)(kr + ((quad ^ sw) * 16));
      s16x8 kf1 = *(const s16x8*)(kr + (((4 + quad) ^ sw) * 16));
      f32x4 st[4];
#pragma unroll
      for (int qf = 0; qf < 4; ++qf) {
        f32x4 a = {};
        a = __builtin_amdgcn_mfma_f32_16x16x32_bf16(kf0, qfr[qf][0], a, 0, 0, 0);
        a = __builtin_amdgcn_mfma_f32_16x16x32_bf16(kf1, qfr[qf][1], a, 0, 0, 0);
        st[qf] = a;
      }
#pragma unroll
      for (int qf = 0; qf < 4; ++qf) {
        float p0 = __builtin_amdgcn_exp2f(st[qf][0]);
        float p1 = __builtin_amdgcn_exp2f(st[qf][1]);
        float p2 = __builtin_amdgcn_exp2f(st[qf][2]);
        float p3 = __builtin_amdgcn_exp2f(st[qf][3]);
        pd[mf][qf][0] = pack_bf2(p0, p1);
        pd[mf][qf][1] = pack_bf2(p2, p3);
      }
    }

    // V^T A-frags from LDS: A[m=d][k=key]
    s16x8 vf[4][2];
#pragma unroll
    for (int df = 0; df < 4; ++df) {
      const char* vr = bV + (df * 16 + l15) * 128;
#pragma unroll
      for (int kh = 0; kh < 2; ++kh)
        vf[df][kh] = *(const s16x8*)(vr + (((kh * 4 + quad) ^ sw) * 16));
    }

    // C-layout -> B-operand layout via gfx950 permlane swaps
#pragma unroll
    for (int kh = 0; kh < 2; ++kh)
#pragma unroll
      for (int qf = 0; qf < 4; ++qf)
#pragma unroll
        for (int pi = 0; pi < 2; ++pi) {
          uint32_t x = pd[2 * kh][qf][pi];
          uint32_t y = pd[2 * kh + 1][qf][pi];
          asm("s_nop 1\n\t"
              "v_permlane32_swap_b32 %0, %1\n\t"
              "s_nop 0\n\t"
              "v_permlane16_swap_b32 %0, %1"
              : "+v"(x), "+v"(y));
          pd[2 * kh][qf][pi] = x;
          pd[2 * kh + 1][qf][pi] = y;
        }

    // PV: out^T += V^T * P^T ; l += 1 * P^T
#pragma unroll
    for (int kh = 0; kh < 2; ++kh)
#pragma unroll
      for (int qf = 0; qf < 4; ++qf) {
        union { s16x8 h; uint32_t u[4]; } bfr;
        bfr.u[0] = pd[2 * kh][qf][0];
        bfr.u[1] = pd[2 * kh][qf][1];
        bfr.u[2] = pd[2 * kh + 1][qf][0];
        bfr.u[3] = pd[2 * kh + 1][qf][1];
#pragma unroll
        for (int df = 0; df < 4; ++df)
          oacc[df][qf] = __builtin_amdgcn_mfma_f32_16x16x32_bf16(vf[df][kh], bfr.h, oacc[df][qf], 0, 0, 0);
        lacc[qf] = __builtin_amdgcn_mfma_f32_16x16x32_bf16(ones, bfr.h, lacc[qf], 0, 0, 0);
      }
  };

  stage(0, 0);
  __syncthreads();
#pragma unroll 1
  for (int t = 0; t < 32; t += 2) {
    if (t + 1 < 32) stage((t + 1) * 64, 1);
    compute(0);
    __syncthreads();
    if (t + 2 < 32) stage((t + 2) * 64, 0);
    compute(1);
    __syncthreads();
  }

  // epilogue: normalize and store bf16 out^T -> attO[b][s][h*64+d]
  const int b = bh >> 4, h = bh & 15;
  float inv[4];
#pragma unroll
  for (int qf = 0; qf < 4; ++qf) inv[qf] = 1.0f / lacc[qf][0];
#pragma unroll
  for (int qf = 0; qf < 4; ++qf) {
    u16* rowp = Od + ((size_t)b * 2048 + q0 + qf * 16 + l15) * 1024 + h * 64;
#pragma unroll
    for (int df = 0; df < 4; ++df) {
      u32x2 w;
      w.x = pack_bf2(oacc[df][qf][0] * inv[qf], oacc[df][qf][1] * inv[qf]);
      w.y = pack_bf2(oacc[df][qf][2] * inv[qf], oacc[df][qf][3] * inv[qf]);
      *(u32x2*)(rowp + df * 16 + quad * 4) = w;
    }
  }
}

extern "C" void kernel_launch(void* const* d_in, const int* in_sizes, int n_in,
                              void* d_out, int out_size, void* d_ws, size_t ws_size,
                              hipStream_t stream) {
  const float* x = (const float*)d_in[0];
  const float* w_qkv = (const float*)d_in[1];
  const float* b_qkv = (const float*)d_in[2];
  const float* w_out = (const float*)d_in[3];
  const float* b_out = (const float*)d_in[4];
  float* out = (float*)d_out;
  char* ws = (char*)d_ws;

  // workspace layout (bytes)
  u16* xb    = (u16*)(ws + 0);         // 16,777,216  x as bf16 [8192][1024]
  u16* wqkvT = (u16*)(ws + 16777216);  //  6,291,456  [3072][1024]
  u16* woutT = (u16*)(ws + 23068672);  //  2,097,152  [1024][1024]
  u16* qw    = (u16*)(ws + 25165824);  // 16,777,216  [64][2048][64] (pre-scaled)
  u16* kw    = (u16*)(ws + 41943040);  // 16,777,216  [64][2048][64]
  u16* vtw   = (u16*)(ws + 58720256);  // 16,777,216  [64][64][2048]
  u16* attO  = (u16*)(ws + 75497472);  // 16,777,216  [8192][1024]
  // total 92,274,688 bytes

  cvt_bf16_kernel<<<8192, 256, 0, stream>>>(x, xb);
  transpose_cvt<<<dim3(96, 32), 256, 0, stream>>>(w_qkv, wqkvT, 1024, 3072);
  transpose_cvt<<<dim3(32, 32), 256, 0, stream>>>(w_out, woutT, 1024, 1024);
  gemm_bt<0><<<dim3(24, 32), 512, 0, stream>>>(xb, wqkvT, b_qkv, qw, kw, vtw, nullptr);
  attn_fused<<<512, 256, 0, stream>>>(qw, kw, vtw, attO);
  gemm_bt<1><<<dim3(8, 32), 512, 0, stream>>>(attO, woutT, b_out, nullptr, nullptr, nullptr, out);
}